// Round 15
// baseline (55.887 us; speedup 1.0000x reference)
//
#include <hip/hip_runtime.h>
#include <hip/hip_bf16.h>
#include <math.h>

#define KL 64      // locations
#define NT 8192    // time steps
#define MF 8       // covariate features
#define DD 32      // memory depth
#define WIN 64     // 2*DD window taps
#define HD 20      // hidden dim
#define HP 32      // hidden padded to 2 MFMA M-tiles
#define KF 512     // 2*DD*MF = GEMM K
#define NB 1024    // cols per block (4 waves x 256)
#define NXB (NT / NB)          // 8 n-tiles
#define NBLK (NXB * KL)        // 512 blocks
#define NPART (NBLK * 4)       // 2048 per-wave partials
#define BPSZ (64 * 32 * 8)     // Bp: [tap=64][hidden=32][feat=8] bf16 = 32 KB

typedef __attribute__((ext_vector_type(8))) short bf16x8;
typedef __attribute__((ext_vector_type(4))) float f32x4;
typedef __attribute__((ext_vector_type(4))) unsigned u32x4;

// fast softplus: v_exp_f32 + v_log_f32
__device__ __forceinline__ float softplus_f(float x) {
    float e = __expf(-fabsf(x));
    return fmaxf(x, 0.0f) + __logf(1.0f + e);
}
__device__ __forceinline__ short f2bf(float x) {
    __hip_bfloat16 h = __float2bfloat16(x);
    return *reinterpret_cast<short*>(&h);
}
// packed f32x2 -> bf16x2 (RNE), single instruction
__device__ __forceinline__ unsigned pkbf(float a, float b) {
    unsigned r;
    asm("v_cvt_pk_bf16_f32 %0, %1, %2" : "=v"(r) : "v"(a), "v"(b));
    return r;
}

// ---- Kernel 1 (tiny): pack W1 A-fragment order, pad b1/W2, FIR table ----
// Bp[(tap*32 + h)*8 + m] = W1[h][tap*8 + m]; h<HD real, h>=HD zero.
__global__ __launch_bounds__(256)
void pack_kernel(const float* __restrict__ W1, const float* __restrict__ b1,
                 const float* __restrict__ W2, const float* __restrict__ hbeta,
                 short* __restrict__ Bp, float* __restrict__ b1p,
                 float* __restrict__ W2p, float* __restrict__ wtab) {
    int t = blockIdx.x * 256 + threadIdx.x;      // grid 16 -> 4096 threads
    #pragma unroll
    for (int i = 0; i < 4; ++i) {
        int p = t + i * 4096;                    // BPSZ = 16384
        int m = p & 7;
        int dc = p >> 3;
        int h = dc & 31;
        int d = dc >> 5;                         // tap 0..63
        Bp[p] = (h < HD) ? f2bf(W1[h * KF + d * 8 + m]) : (short)0;
    }
    if (blockIdx.x == 0 && threadIdx.x < HP) {
        b1p[threadIdx.x] = (threadIdx.x < HD) ? b1[threadIdx.x] : 0.0f;
        W2p[threadIdx.x] = (threadIdx.x < HD) ? W2[threadIdx.x] : 0.0f;
    }
    if (blockIdx.x == 0 && threadIdx.x < WIN) {
        float bt = hbeta[0];
        wtab[threadIdx.x] = bt * __expf(-bt * (float)(threadIdx.x + 1));
    }
}

// ---- Kernel 2: wave-independent, swapped-operand MFMA, 256 cols/wave ----
// Per wave: 16 time-tiles of 16 (acc[16][2] -> 128 AGPRs), one 320-row cov
// window, one 320-entry T slice. W1 A-fragments (32 loads/wave) amortize over
// 256 cols; lane owns output rows base+64q+lane, q=0..3 (quad FIR shares the
// wt s_loads). Zero __syncthreads (wave-private LDS).
__global__ __launch_bounds__(256)
void mlp_mfma_kernel(const float* __restrict__ covs, const float* __restrict__ obs,
                     const float* __restrict__ halpha, const float* __restrict__ hbeta,
                     const short* __restrict__ Bp, const float* __restrict__ b1p,
                     const float* __restrict__ W2p, const float* __restrict__ b2,
                     const float* __restrict__ gamma, const float* __restrict__ wt,
                     float* __restrict__ lams, float* __restrict__ partial) {
    __shared__ short cov_s[4][320 * MF];   // per-wave [320 rows][8] bf16 (20 KB)
    __shared__ float T_s[4][320];          // per-wave T slice [base-64, base+256)

    int k    = blockIdx.y;
    int n0   = blockIdx.x * NB;
    int tid  = threadIdx.x;
    int lane = tid & 63;
    int wave = tid >> 6;
    int base = n0 + wave * 256;
    int c    = lane & 15;
    int g    = lane >> 4;

    // hoisted scalars/loads (lane owns rows base+64q+lane)
    int n = base + lane;
    size_t idx = (size_t)k * NT + n;
    float obs_n0 = obs[idx];
    float obs_n1 = obs[idx + 64];
    float obs_n2 = obs[idx + 128];
    float obs_n3 = obs[idx + 192];
    float beta  = hbeta[0];
    float gam   = gamma[k];
    float b2v   = b2[0];

    // ---- stage this wave's cov window [base-32, base+288), 5 rows/lane ----
    const float* cbase = covs + (size_t)k * NT * MF;
    #pragma unroll
    for (int s = 0; s < 5; ++s) {
        int tt = base - DD + s * 64 + lane;
        tt = tt < 0 ? 0 : (tt > NT - 1 ? NT - 1 : tt);
        const float4* cp = (const float4*)(cbase + (size_t)tt * MF);
        float4 a0 = cp[0], a1 = cp[1];
        u32x4 q = { pkbf(a0.x, a0.y), pkbf(a0.z, a0.w),
                    pkbf(a1.x, a1.y), pkbf(a1.z, a1.w) };
        *(u32x4*)&cov_s[wave][(s * 64 + lane) * MF] = q;
    }

    f32x4 acc[16][2];
    #pragma unroll
    for (int mt = 0; mt < 16; ++mt) {
        acc[mt][0] = (f32x4){0.f, 0.f, 0.f, 0.f};
        acc[mt][1] = (f32x4){0.f, 0.f, 0.f, 0.f};
    }

    // A (W1): lane base offset g*256 + c*8 shorts; +kk*1024 (+128 for ht=1)
    const short* pAw = Bp + g * 256 + c * 8;
    // B (cov): lane reads local row c + g + mt*16 + kk*4 (max 315 < 320)
    const short* pBc = &cov_s[wave][(c + g) * MF];

    // T-dot: T_s[wave][r] = dot(halpha[k,:], obs[:, base-64+r]), r=0..319,
    // 5 chains/lane interleaved 4 j-steps per kk.
    const float* arow = halpha + (size_t)k * KL;   // wave-uniform -> s_load
    int i0 = base - WIN + lane;
    i0 = i0 < 0 ? 0 : i0;                          // clamped entries guarded in FIR
    int i1 = base + lane;                          // in [0, NT)
    int i2 = base + 64 + lane;
    int i3 = base + 128 + lane;
    int i4 = base + 192 + lane;                    // max 8191, in-bounds
    float aT0 = 0.f, aT1 = 0.f, aT2 = 0.f, aT3 = 0.f, aT4 = 0.f;

    #pragma unroll 2
    for (int kk = 0; kk < KF / 32; ++kk) {
        #pragma unroll
        for (int jj = 0; jj < 4; ++jj) {
            int j = kk * 4 + jj;
            float ajv = arow[j];
            const float* orow = obs + (size_t)j * NT;
            aT0 = fmaf(ajv, orow[i0], aT0);
            aT1 = fmaf(ajv, orow[i1], aT1);
            aT2 = fmaf(ajv, orow[i2], aT2);
            aT3 = fmaf(ajv, orow[i3], aT3);
            aT4 = fmaf(ajv, orow[i4], aT4);
        }
        bf16x8 aw0 = *(const bf16x8*)(pAw + kk * 1024);
        bf16x8 aw1 = *(const bf16x8*)(pAw + kk * 1024 + 128);
        #pragma unroll
        for (int mt = 0; mt < 16; ++mt) {
            bf16x8 bc = *(const bf16x8*)(pBc + (mt * 16 + kk * 4) * MF);
            acc[mt][0] = __builtin_amdgcn_mfma_f32_16x16x32_bf16(aw0, bc, acc[mt][0], 0, 0, 0);
            acc[mt][1] = __builtin_amdgcn_mfma_f32_16x16x32_bf16(aw1, bc, acc[mt][1], 0, 0, 0);
        }
    }
    T_s[wave][lane] = aT0;
    T_s[wave][64 + lane] = aT1;
    T_s[wave][128 + lane] = aT2;
    T_s[wave][192 + lane] = aT3;
    T_s[wave][256 + lane] = aT4;

    // ---- epilogue: lane-local softplus+W2 dot, 2-shfl g-reduce per time-tile ----
    // acc[mt][ht][r] = h_pre[hidden ht*16+g*4+r][time base + mt*16 + c].
    // Lane keeps tile mt = 4q+g (its row 64q+lane = base + (4q+g)*16 + c).
    float4 w2lo = *(const float4*)&W2p[g * 4];
    float4 w2hi = *(const float4*)&W2p[16 + g * 4];
    float4 b1lo = *(const float4*)&b1p[g * 4];
    float4 b1hi = *(const float4*)&b1p[16 + g * 4];
    float pre0 = 0.f, pre1 = 0.f, pre2 = 0.f, pre3 = 0.f;
    #pragma unroll
    for (int mt = 0; mt < 16; ++mt) {
        float p = 0.0f;
        #pragma unroll
        for (int r = 0; r < 4; ++r) {
            p = fmaf(((const float*)&w2lo)[r],
                     softplus_f(acc[mt][0][r] + ((const float*)&b1lo)[r]), p);
            p = fmaf(((const float*)&w2hi)[r],
                     softplus_f(acc[mt][1][r] + ((const float*)&b1hi)[r]), p);
        }
        p += __shfl_xor(p, 16, 64);
        p += __shfl_xor(p, 32, 64);
        if (mt < 4)       pre0 = (g == mt)      ? p : pre0;
        else if (mt < 8)  pre1 = (g == mt - 4)  ? p : pre1;
        else if (mt < 12) pre2 = (g == mt - 8)  ? p : pre2;
        else              pre3 = (g == mt - 12) ? p : pre3;
    }

    // ---- quad FIR on own T slice (shared wt s_loads), lam, loglik ----
    // Static path (base>=WIN, beta>=5/3): 20 taps. Tail: T<=0.64, beta*L>=30
    // -> err ~1e-13.
    const float* Tq0 = &T_s[wave][64 + lane];
    const float* Tq1 = &T_s[wave][128 + lane];
    const float* Tq2 = &T_s[wave][192 + lane];
    const float* Tq3 = &T_s[wave][256 + lane];
    float la0 = 0.f, la1 = 0.f, la2 = 0.f, la3 = 0.f;
    if (base >= WIN && beta >= 1.6667f) {
        #pragma unroll
        for (int it = 0; it < 5; ++it) {
            #pragma unroll
            for (int u = 0; u < 4; ++u) {
                float w = wt[4 * it + u];
                int off = 4 * it + u + 1;
                la0 = fmaf(w, Tq0[-off], la0);
                la1 = fmaf(w, Tq1[-off], la1);
                la2 = fmaf(w, Tq2[-off], la2);
                la3 = fmaf(w, Tq3[-off], la3);
            }
        }
    } else {                                   // block-0-wave-0 / small-beta path
        float decay = __expf(-beta);
        int Lmax = (int)(30.0f / beta) + 2;
        if (Lmax > WIN) Lmax = WIN;
        float w = beta * decay;
        for (int i = 1; i <= Lmax; ++i) {
            if (i <= n)       la0 = fmaf(w, Tq0[-i], la0);
            if (i <= n + 64)  la1 = fmaf(w, Tq1[-i], la1);
            if (i <= n + 128) la2 = fmaf(w, Tq2[-i], la2);
            if (i <= n + 192) la3 = fmaf(w, Tq3[-i], la3);
            w *= decay;
        }
    }
    float lamA = softplus_f(la0) + gam * softplus_f(pre0 + b2v);
    float lamB = softplus_f(la1) + gam * softplus_f(pre1 + b2v);
    float lamC = softplus_f(la2) + gam * softplus_f(pre2 + b2v);
    float lamD = softplus_f(la3) + gam * softplus_f(pre3 + b2v);
    lams[idx]       = lamA;
    lams[idx + 64]  = lamB;
    lams[idx + 128] = lamC;
    lams[idx + 192] = lamD;
    float term = fmaf(obs_n0, __logf(lamA), -lamA)
               + fmaf(obs_n1, __logf(lamB), -lamB)
               + fmaf(obs_n2, __logf(lamC), -lamC)
               + fmaf(obs_n3, __logf(lamD), -lamD);

    #pragma unroll
    for (int off = 32; off > 0; off >>= 1) term += __shfl_down(term, off, 64);
    if (lane == 0)
        partial[((size_t)blockIdx.y * NXB + blockIdx.x) * 4 + wave] = term;
}

// ---- Kernel 3: sum 2048 per-wave partials -> out[0] ----
__global__ __launch_bounds__(256)
void finalize_kernel(const float* __restrict__ partial, float* __restrict__ out0) {
    __shared__ float wred[4];
    int tid = threadIdx.x;
    float s = 0.0f;
    #pragma unroll
    for (int i = 0; i < NPART / 256; ++i) s += partial[i * 256 + tid];
    #pragma unroll
    for (int off = 32; off > 0; off >>= 1) s += __shfl_down(s, off, 64);
    if ((tid & 63) == 0) wred[tid >> 6] = s;
    __syncthreads();
    if (tid == 0) out0[0] = (wred[0] + wred[1]) + (wred[2] + wred[3]);
}

extern "C" void kernel_launch(void* const* d_in, const int* in_sizes, int n_in,
                              void* d_out, int out_size, void* d_ws, size_t ws_size,
                              hipStream_t stream) {
    const float* obs    = (const float*)d_in[0];
    const float* covs   = (const float*)d_in[1];
    const float* hbeta  = (const float*)d_in[2];
    const float* halpha = (const float*)d_in[3];
    const float* gamma  = (const float*)d_in[4];
    const float* W1     = (const float*)d_in[5];
    const float* b1     = (const float*)d_in[6];
    const float* W2     = (const float*)d_in[7];
    const float* b2     = (const float*)d_in[8];

    float* out  = (float*)d_out;   // out[0]=loglik, out[1..]=lams [K][N]
    float* lams = out + 1;

    char* ws = (char*)d_ws;
    float* partial = (float*)ws;                 // 8 KB (2048 per-wave partials)
    float* b1p     = (float*)(ws + 32768);       // 128 B
    float* W2p     = (float*)(ws + 32896);       // 128 B
    float* wtab    = (float*)(ws + 33024);       // 256 B FIR weights
    short* Bp      = (short*)(ws + 33280);       // 32 KB, 16B aligned

    pack_kernel<<<dim3(16), dim3(256), 0, stream>>>(W1, b1, W2, hbeta,
                                                    Bp, b1p, W2p, wtab);
    mlp_mfma_kernel<<<dim3(NXB, KL), dim3(256), 0, stream>>>(
        covs, obs, halpha, hbeta, Bp, b1p, W2p, b2, gamma, wtab, lams, partial);
    finalize_kernel<<<1, dim3(256), 0, stream>>>(partial, out);
}

// Round 16
// 39.728 us; speedup vs baseline: 1.4067x; 1.4067x over previous
//
#include <hip/hip_runtime.h>
#include <hip/hip_bf16.h>
#include <math.h>

#define KL 64      // locations
#define NT 8192    // time steps
#define MF 8       // covariate features
#define DD 32      // memory depth
#define WIN 64     // 2*DD window taps
#define HD 20      // hidden dim
#define HP 32      // hidden padded to 2 MFMA M-tiles
#define KF 512     // 2*DD*MF = GEMM K
#define NB 512     // cols per block (4 waves x 128)
#define NXB (NT / NB)          // 16 n-tiles
#define NBLK (NXB * KL)        // 1024 blocks
#define NPART (NBLK * 4)       // 4096 per-wave partials
#define BPSZ (64 * 32 * 8)     // Bp: [tap=64][hidden=32][feat=8] bf16 = 32 KB

typedef __attribute__((ext_vector_type(8))) short bf16x8;
typedef __attribute__((ext_vector_type(4))) float f32x4;
typedef __attribute__((ext_vector_type(4))) unsigned u32x4;

// fast softplus: v_exp_f32 + v_log_f32
__device__ __forceinline__ float softplus_f(float x) {
    float e = __expf(-fabsf(x));
    return fmaxf(x, 0.0f) + __logf(1.0f + e);
}
__device__ __forceinline__ short f2bf(float x) {
    __hip_bfloat16 h = __float2bfloat16(x);
    return *reinterpret_cast<short*>(&h);
}
// packed f32x2 -> bf16x2 (RNE), single instruction
__device__ __forceinline__ unsigned pkbf(float a, float b) {
    unsigned r;
    asm("v_cvt_pk_bf16_f32 %0, %1, %2" : "=v"(r) : "v"(a), "v"(b));
    return r;
}

// ---- Kernel 1 (tiny): pack W1 A-fragment order, pad b1/W2, FIR table ----
// Bp[(tap*32 + h)*8 + m] = W1[h][tap*8 + m]; h<HD real, h>=HD zero.
__global__ __launch_bounds__(256)
void pack_kernel(const float* __restrict__ W1, const float* __restrict__ b1,
                 const float* __restrict__ W2, const float* __restrict__ hbeta,
                 short* __restrict__ Bp, float* __restrict__ b1p,
                 float* __restrict__ W2p, float* __restrict__ wtab) {
    int t = blockIdx.x * 256 + threadIdx.x;      // grid 16 -> 4096 threads
    #pragma unroll
    for (int i = 0; i < 4; ++i) {
        int p = t + i * 4096;                    // BPSZ = 16384
        int m = p & 7;
        int dc = p >> 3;
        int h = dc & 31;
        int d = dc >> 5;                         // tap 0..63
        Bp[p] = (h < HD) ? f2bf(W1[h * KF + d * 8 + m]) : (short)0;
    }
    if (blockIdx.x == 0 && threadIdx.x < HP) {
        b1p[threadIdx.x] = (threadIdx.x < HD) ? b1[threadIdx.x] : 0.0f;
        W2p[threadIdx.x] = (threadIdx.x < HD) ? W2[threadIdx.x] : 0.0f;
    }
    if (blockIdx.x == 0 && threadIdx.x < WIN) {
        float bt = hbeta[0];
        wtab[threadIdx.x] = bt * __expf(-bt * (float)(threadIdx.x + 1));
    }
}

// ---- Kernel 2: wave-independent, swapped-operand MFMA, 128 cols/wave ----
// Measured tile optimum (64/128/256 cols/wave = 41.7/40.0/55.9 us): 128 cols
// balances per-output fixed-cost amortization against resident concurrency
// (4096 waves = 16/CU, one full round). acc[8][2] rides in AGPRs (unified
// file); W1 A-fragments from L1 amortize over 2x output; lane owns rows
// base+lane and base+64+lane. Zero __syncthreads (wave-private LDS).
__global__ __launch_bounds__(256)
void mlp_mfma_kernel(const float* __restrict__ covs, const float* __restrict__ obs,
                     const float* __restrict__ halpha, const float* __restrict__ hbeta,
                     const short* __restrict__ Bp, const float* __restrict__ b1p,
                     const float* __restrict__ W2p, const float* __restrict__ b2,
                     const float* __restrict__ gamma, const float* __restrict__ wt,
                     float* __restrict__ lams, float* __restrict__ partial) {
    __shared__ short cov_s[4][192 * MF];   // per-wave [192 rows][8] bf16 (12 KB)
    __shared__ float T_s[4][192];          // per-wave T slice [base-64, base+128)

    int k    = blockIdx.y;
    int n0   = blockIdx.x * NB;
    int tid  = threadIdx.x;
    int lane = tid & 63;
    int wave = tid >> 6;
    int base = n0 + wave * 128;
    int c    = lane & 15;
    int g    = lane >> 4;

    // hoisted scalars/loads (lane owns rows base+lane, base+64+lane)
    int n = base + lane;
    size_t idx = (size_t)k * NT + n;
    float obs_n0 = obs[idx];
    float obs_n1 = obs[idx + 64];
    float beta  = hbeta[0];
    float gam   = gamma[k];
    float b2v   = b2[0];

    // ---- stage this wave's cov window [base-32, base+160), 3 rows/lane ----
    const float* cbase = covs + (size_t)k * NT * MF;
    {
        int t1 = base - DD + lane;                 // [base-32, base+32)
        t1 = t1 < 0 ? 0 : t1;
        int t2 = base + DD + lane;                 // [base+32, base+96), in-bounds
        int t3 = base + 96 + lane;                 // [base+96, base+160)
        t3 = t3 > NT - 1 ? NT - 1 : t3;
        const float4* cp1 = (const float4*)(cbase + (size_t)t1 * MF);
        const float4* cp2 = (const float4*)(cbase + (size_t)t2 * MF);
        const float4* cp3 = (const float4*)(cbase + (size_t)t3 * MF);
        float4 a0 = cp1[0], a1 = cp1[1];
        float4 d0 = cp2[0], d1 = cp2[1];
        float4 e0 = cp3[0], e1 = cp3[1];
        u32x4 q1 = { pkbf(a0.x, a0.y), pkbf(a0.z, a0.w),
                     pkbf(a1.x, a1.y), pkbf(a1.z, a1.w) };
        u32x4 q2 = { pkbf(d0.x, d0.y), pkbf(d0.z, d0.w),
                     pkbf(d1.x, d1.y), pkbf(d1.z, d1.w) };
        u32x4 q3 = { pkbf(e0.x, e0.y), pkbf(e0.z, e0.w),
                     pkbf(e1.x, e1.y), pkbf(e1.z, e1.w) };
        *(u32x4*)&cov_s[wave][lane * MF] = q1;
        *(u32x4*)&cov_s[wave][(lane + 64) * MF] = q2;
        *(u32x4*)&cov_s[wave][(lane + 128) * MF] = q3;
    }

    f32x4 acc[8][2];
    #pragma unroll
    for (int mt = 0; mt < 8; ++mt) {
        acc[mt][0] = (f32x4){0.f, 0.f, 0.f, 0.f};
        acc[mt][1] = (f32x4){0.f, 0.f, 0.f, 0.f};
    }

    // A (W1): lane base offset g*256 + c*8 shorts; +kk*1024 (+128 for ht=1)
    const short* pAw = Bp + g * 256 + c * 8;
    // B (cov): lane reads local row c + g + mt*16 + kk*4 (max 190 < 192)
    const short* pBc = &cov_s[wave][(c + g) * MF];

    // T-dot: T_s[wave][r] = dot(halpha[k,:], obs[:, base-64+r]), r=0..191,
    // 3 chains/lane interleaved 4 j-steps per kk.
    const float* arow = halpha + (size_t)k * KL;   // wave-uniform -> s_load
    int tA = base - WIN + lane;
    tA = tA < 0 ? 0 : tA;                          // clamped entries guarded in FIR
    int tB = base + lane;                          // in [0, NT)
    int tC = base + 64 + lane;                     // max 8191, in [0, NT)
    float aA = 0.0f, aB = 0.0f, aC = 0.0f;

    #pragma unroll 2
    for (int kk = 0; kk < KF / 32; ++kk) {
        #pragma unroll
        for (int jj = 0; jj < 4; ++jj) {
            int j = kk * 4 + jj;
            float ajv = arow[j];
            const float* orow = obs + (size_t)j * NT;
            aA = fmaf(ajv, orow[tA], aA);
            aB = fmaf(ajv, orow[tB], aB);
            aC = fmaf(ajv, orow[tC], aC);
        }
        bf16x8 aw0 = *(const bf16x8*)(pAw + kk * 1024);
        bf16x8 aw1 = *(const bf16x8*)(pAw + kk * 1024 + 128);
        #pragma unroll
        for (int mt = 0; mt < 8; ++mt) {
            bf16x8 bc = *(const bf16x8*)(pBc + (mt * 16 + kk * 4) * MF);
            acc[mt][0] = __builtin_amdgcn_mfma_f32_16x16x32_bf16(aw0, bc, acc[mt][0], 0, 0, 0);
            acc[mt][1] = __builtin_amdgcn_mfma_f32_16x16x32_bf16(aw1, bc, acc[mt][1], 0, 0, 0);
        }
    }
    T_s[wave][lane] = aA;
    T_s[wave][64 + lane] = aB;
    T_s[wave][128 + lane] = aC;

    // ---- epilogue: lane-local softplus+W2 dot, 2-shfl g-reduce per time-tile ----
    // acc[mt][ht][r] = h_pre[hidden ht*16+g*4+r][time base + mt*16 + c].
    // Lane keeps tiles mt==g (row lane) and mt==4+g (row 64+lane).
    float4 w2lo = *(const float4*)&W2p[g * 4];       // loaded post-loop: less
    float4 w2hi = *(const float4*)&W2p[16 + g * 4];  // mid-loop reg pressure
    float4 b1lo = *(const float4*)&b1p[g * 4];
    float4 b1hi = *(const float4*)&b1p[16 + g * 4];
    float pre0 = 0.0f, pre1 = 0.0f;
    #pragma unroll
    for (int mt = 0; mt < 8; ++mt) {
        float p = 0.0f;
        #pragma unroll
        for (int r = 0; r < 4; ++r) {
            p = fmaf(((const float*)&w2lo)[r],
                     softplus_f(acc[mt][0][r] + ((const float*)&b1lo)[r]), p);
            p = fmaf(((const float*)&w2hi)[r],
                     softplus_f(acc[mt][1][r] + ((const float*)&b1hi)[r]), p);
        }
        p += __shfl_xor(p, 16, 64);
        p += __shfl_xor(p, 32, 64);
        if (mt < 4) pre0 = (g == mt)     ? p : pre0;   // row g*16+c = lane
        else        pre1 = (g == mt - 4) ? p : pre1;   // row 64+lane
    }

    // ---- dual FIR on own T slice (shared wt s_loads), lam, loglik ----
    // Static path (base>=WIN, beta>=5/3): 20 taps. Tail: T<=0.64, beta*L>=30
    // -> err ~1e-13.
    const float* Tp0 = &T_s[wave][64 + lane];
    const float* Tp1 = &T_s[wave][128 + lane];
    float la0v = 0.0f, la1v = 0.0f;
    if (base >= WIN && beta >= 1.6667f) {
        float s00 = 0.f, s01 = 0.f, s02 = 0.f, s03 = 0.f;
        float s10 = 0.f, s11 = 0.f, s12 = 0.f, s13 = 0.f;
        #pragma unroll
        for (int it = 0; it < 5; ++it) {
            float w0 = wt[4 * it + 0], w1 = wt[4 * it + 1];
            float w2 = wt[4 * it + 2], w3 = wt[4 * it + 3];
            s00 = fmaf(w0, Tp0[-(4 * it + 1)], s00);
            s10 = fmaf(w0, Tp1[-(4 * it + 1)], s10);
            s01 = fmaf(w1, Tp0[-(4 * it + 2)], s01);
            s11 = fmaf(w1, Tp1[-(4 * it + 2)], s11);
            s02 = fmaf(w2, Tp0[-(4 * it + 3)], s02);
            s12 = fmaf(w2, Tp1[-(4 * it + 3)], s12);
            s03 = fmaf(w3, Tp0[-(4 * it + 4)], s03);
            s13 = fmaf(w3, Tp1[-(4 * it + 4)], s13);
        }
        la0v = (s00 + s01) + (s02 + s03);
        la1v = (s10 + s11) + (s12 + s13);
    } else {                                   // block-0-wave-0 / small-beta path
        float decay = __expf(-beta);
        int Lmax = (int)(30.0f / beta) + 2;
        if (Lmax > WIN) Lmax = WIN;
        float w = beta * decay;
        int n2 = n + 64;
        for (int i = 1; i <= Lmax; ++i) {
            if (i <= n)  la0v = fmaf(w, Tp0[-i], la0v);
            if (i <= n2) la1v = fmaf(w, Tp1[-i], la1v);
            w *= decay;
        }
    }
    float lamA = softplus_f(la0v) + gam * softplus_f(pre0 + b2v);
    float lamB = softplus_f(la1v) + gam * softplus_f(pre1 + b2v);
    lams[idx] = lamA;
    lams[idx + 64] = lamB;
    float term = fmaf(obs_n0, __logf(lamA), -lamA)
               + fmaf(obs_n1, __logf(lamB), -lamB);

    #pragma unroll
    for (int off = 32; off > 0; off >>= 1) term += __shfl_down(term, off, 64);
    if (lane == 0)
        partial[((size_t)blockIdx.y * NXB + blockIdx.x) * 4 + wave] = term;
}

// ---- Kernel 3: sum 4096 per-wave partials -> out[0] ----
__global__ __launch_bounds__(256)
void finalize_kernel(const float* __restrict__ partial, float* __restrict__ out0) {
    __shared__ float wred[4];
    int tid = threadIdx.x;
    float s = 0.0f;
    #pragma unroll
    for (int i = 0; i < NPART / 256; ++i) s += partial[i * 256 + tid];
    #pragma unroll
    for (int off = 32; off > 0; off >>= 1) s += __shfl_down(s, off, 64);
    if ((tid & 63) == 0) wred[tid >> 6] = s;
    __syncthreads();
    if (tid == 0) out0[0] = (wred[0] + wred[1]) + (wred[2] + wred[3]);
}

extern "C" void kernel_launch(void* const* d_in, const int* in_sizes, int n_in,
                              void* d_out, int out_size, void* d_ws, size_t ws_size,
                              hipStream_t stream) {
    const float* obs    = (const float*)d_in[0];
    const float* covs   = (const float*)d_in[1];
    const float* hbeta  = (const float*)d_in[2];
    const float* halpha = (const float*)d_in[3];
    const float* gamma  = (const float*)d_in[4];
    const float* W1     = (const float*)d_in[5];
    const float* b1     = (const float*)d_in[6];
    const float* W2     = (const float*)d_in[7];
    const float* b2     = (const float*)d_in[8];

    float* out  = (float*)d_out;   // out[0]=loglik, out[1..]=lams [K][N]
    float* lams = out + 1;

    char* ws = (char*)d_ws;
    float* partial = (float*)ws;                 // 16 KB (4096 per-wave partials)
    float* b1p     = (float*)(ws + 32768);       // 128 B
    float* W2p     = (float*)(ws + 32896);       // 128 B
    float* wtab    = (float*)(ws + 33024);       // 256 B FIR weights
    short* Bp      = (short*)(ws + 33280);       // 32 KB, 16B aligned

    pack_kernel<<<dim3(16), dim3(256), 0, stream>>>(W1, b1, W2, hbeta,
                                                    Bp, b1p, W2p, wtab);
    mlp_mfma_kernel<<<dim3(NXB, KL), dim3(256), 0, stream>>>(
        covs, obs, halpha, hbeta, Bp, b1p, W2p, b2, gamma, wtab, lams, partial);
    finalize_kernel<<<1, dim3(256), 0, stream>>>(partial, out);
}